// Round 19
// baseline (73.718 us; speedup 1.0000x reference)
//
#include <hip/hip_runtime.h>
#include <hip/hip_bf16.h>

// 2D DCT-II (4096x4096 fp32).  Round 19:
//   K1  = dct_rows4 v3 (direct Makhoul load, single 33KB pane, 7 barriers)
//   K2a = cooperative column step 1 (unchanged)
//   K2b = v4: the two FFT64s run in PARALLEL ACROSS WAVE-HALVES (1024 thr,
//         h=0 -> Gq, h=1 -> Gq2, each in its own 32KB pane) instead of
//         serially.  Per-thread state halves (8 float2), barriers 5 -> 3.
//         Combine: partner pane = self0 ? h : 1-h, reflection
//         (q_h==0) ? (64-p)&63 : 63-p  (R15 algebra, re-verified).
// Plan: K1(x->out) ; K2a(out->ws) ; K2b(ws->out).  d_ws needs 64 MB.

#define L 4096

__device__ __forceinline__ float2 cmul(float2 a, float2 b) {
    return make_float2(a.x * b.x - a.y * b.y, a.x * b.y + a.y * b.x);
}

__device__ __forceinline__ void bfly4(float2& x0, float2& x1, float2& x2, float2& x3) {
    float t0x = x0.x + x2.x, t0y = x0.y + x2.y;
    float t1x = x0.x - x2.x, t1y = x0.y - x2.y;
    float t2x = x1.x + x3.x, t2y = x1.y + x3.y;
    float t3x = x1.x - x3.x, t3y = x1.y - x3.y;
    x0 = make_float2(t0x + t2x, t0y + t2y);
    x1 = make_float2(t1x + t3y, t1y - t3x);   // t1 + (-i)*t3
    x2 = make_float2(t0x - t2x, t0y - t2y);
    x3 = make_float2(t1x - t3y, t1y + t3x);   // t1 + (+i)*t3
}

#define FOR8(X) X(0) X(1) X(2) X(3) X(4) X(5) X(6) X(7)

// 8-point DFT on named regs P0..P7, natural in -> natural out (DIT):
#define FFT8N(P) \
  bfly4(P##0, P##2, P##4, P##6); \
  bfly4(P##1, P##3, P##5, P##7); \
  { float2 e1_=P##2, e2_=P##4, e3_=P##6, o0_=P##1, o1_=P##3, o2_=P##5, o3_=P##7; \
    o1_ = cmul(o1_, make_float2(0.70710678118654752f, -0.70710678118654752f)); \
    o2_ = make_float2(o2_.y, -o2_.x); \
    o3_ = cmul(o3_, make_float2(-0.70710678118654752f, -0.70710678118654752f)); \
    float2 e0_=P##0; \
    P##0 = make_float2(e0_.x+o0_.x, e0_.y+o0_.y); \
    P##4 = make_float2(e0_.x-o0_.x, e0_.y-o0_.y); \
    P##1 = make_float2(e1_.x+o1_.x, e1_.y+o1_.y); \
    P##5 = make_float2(e1_.x-o1_.x, e1_.y-o1_.y); \
    P##2 = make_float2(e2_.x+o2_.x, e2_.y+o2_.y); \
    P##6 = make_float2(e2_.x-o2_.x, e2_.y-o2_.y); \
    P##3 = make_float2(e3_.x+o3_.x, e3_.y+o3_.y); \
    P##7 = make_float2(e3_.x-o3_.x, e3_.y-o3_.y); }

#define TWCHAIN(P, W) { float2 f_ = W; \
    P##1 = cmul(P##1, f_); f_ = cmul(f_, W); \
    P##2 = cmul(P##2, f_); f_ = cmul(f_, W); \
    P##3 = cmul(P##3, f_); f_ = cmul(f_, W); \
    P##4 = cmul(P##4, f_); f_ = cmul(f_, W); \
    P##5 = cmul(P##5, f_); f_ = cmul(f_, W); \
    P##6 = cmul(P##6, f_); f_ = cmul(f_, W); \
    P##7 = cmul(P##7, f_); }

// ---------------- K1: cooperative row DCT, v3 (unchanged) ----------------
__global__ __launch_bounds__(512)
void dct_rows4_kernel(const float* __restrict__ in, float* __restrict__ out) {
    __shared__ float2 xch[4160];            // 33,280 B -> 4 blocks/CU
    const int l = threadIdx.x & 63;
    const int v = threadIdx.x >> 6;
    const int r0 = blockIdx.x * 2;
    const float* rowA = in + (size_t)r0 * L;
    const float* rowB = rowA + L;

#define LD(u) float2 g##u; { \
        const int n = 512*u + 64*v + l; \
        const int ix = (u < 4) ? (2*n) : (8191 - 2*n); \
        g##u = make_float2(rowA[ix], rowB[ix]); }
    FOR8(LD)
#undef LD

    FFT8N(g)
#define W2(t) xch[512*v + 64*t + l] = g##t;
    FOR8(W2)
#undef W2
    __syncthreads();                        // B1
#define R2(vv) g##vv = xch[512*vv + 64*v + l];
    FOR8(R2)
#undef R2
    __syncthreads();                        // B2 (WAR)

    float2 wv; __sincosf((float)v * -0.09817477042468103f, &wv.y, &wv.x); // -2pi v/64
    TWCHAIN(g, wv)
    FFT8N(g)                                // -> H[q = 8s+v][b = l] in g_s

    float2 mw, ms;
    __sincosf((float)(l * v) * -1.5339807878856412e-3f, &mw.y, &mw.x);
    __sincosf((float)l * -1.2271846303085130e-2f, &ms.y, &ms.x);
#define W3(s) { g##s = cmul(g##s, mw); xch[520*s + 65*v + l] = g##s; mw = cmul(mw, ms); }
    FOR8(W3)
#undef W3
    __syncthreads();                        // B3
#define R3(u) g##u = xch[65*l + 8*u + v];
    FOR8(R3)
#undef R3
    __syncthreads();                        // B4 (WAR)

    FFT8N(g)
#define W4(t) xch[512*v + 64*t + l] = g##t;
    FOR8(W4)
#undef W4
    __syncthreads();                        // B5
#define R4(vv) g##vv = xch[512*vv + 64*v + l];
    FOR8(R4)
#undef R4
    __syncthreads();                        // B6 (WAR)

    TWCHAIN(g, wv)
    FFT8N(g)                                // -> X[512s + 64v + l] in g_s

#define W5(s) xch[520*s + 65*v + l] = g##s;
    FOR8(W5)
#undef W5
    __syncthreads();                        // B7

    float* outA = out + (size_t)r0 * L;
    float* outB = outA + L;
    float2 e; __sincosf((float)(64*v + l) * 3.8349519697141029e-4f, &e.y, &e.x); // pi k0/8192
    const float2 ST = make_float2(0.98078528040323045f, 0.19509032201612827f);   // e^{i pi/16}
#define EP5(s) { \
        const int k = 512*s + 64*v + l; \
        const int m = (4096 - k) & 4095; \
        float2 Zk = g##s; \
        float2 Zm = xch[(m >> 6) * 65 + (m & 63)]; \
        float vax = 0.5f*(Zk.x + Zm.x), vay = 0.5f*(Zk.y - Zm.y); \
        float vbx = 0.5f*(Zk.y + Zm.y), vby = 0.5f*(Zm.x - Zk.x); \
        outA[k] = vax*e.x + vay*e.y; \
        outB[k] = vbx*e.x + vby*e.y; \
        e = cmul(e, ST); }
    FOR8(EP5)
#undef EP5
}

// ---------------- K2a: cooperative column pass, step 1 (unchanged) ----------------
__global__ __launch_bounds__(512)
void fft64_col_a2(const float* __restrict__ Y, float* __restrict__ ws) {
    __shared__ float2 xch[4096];            // [v][t][c], 32 KB
    const int c = threadIdx.x & 63;
    const int v = threadIdx.x >> 6;         // 0..7
    const int b = blockIdx.x;               // 0..63
    const int T = blockIdx.y;               // 0..31
    const int ca = T * 128 + c;
    const int cb = ca + 64;

#define LDA(u) float2 g##u; { \
        const int aa = 8 * u + v; \
        const int row = (u < 4) ? (128 * aa + 2 * b) : (8191 - 128 * aa - 2 * b); \
        const float* rp = Y + (size_t)row * L; \
        g##u = make_float2(rp[ca], rp[cb]); }
    FOR8(LDA)
#undef LDA

    FFT8N(g)                                // over u -> G[t][v] in g_t

#define WRA(t) xch[v * 512 + t * 64 + c] = g##t;
    FOR8(WRA)
#undef WRA
    __syncthreads();
#define RDA(vv) g##vv = xch[vv * 512 + v * 64 + c];
    FOR8(RDA)
#undef RDA

    float2 wv; __sincosf((float)v * -0.09817477042468103f, &wv.y, &wv.x); // -2pi v/64
    TWCHAIN(g, wv)

    FFT8N(g)                                // -> Z[q], q = 8s+v, in g_s

    float2 mw, ms;
    __sincosf((float)(b * v) * -1.5339807878856412e-3f, &mw.y, &mw.x);
    __sincosf((float)b * -1.2271846303085130e-2f, &ms.y, &ms.x);   // -pi b/256
    float2* wp = reinterpret_cast<float2*>(ws) + (size_t)b * 2048 + (size_t)T * 64 + c;
#define STA(s) { \
        g##s = cmul(g##s, mw); \
        wp[(size_t)(8 * s + v) * 131072] = g##s; \
        mw = cmul(mw, ms); }
    FOR8(STA)
#undef STA
}

// ---------------- K2b v4: parallel-halves column pass, step 2 ----------------
// 1024 threads: (c, v, h).  Half h computes G_h = FFT64_b(H[q_h]) in pane h;
// combine uses partner pane (self0 ? h : 1-h) with reflection
// (q_h==0) ? (64-p)&63 : 63-p.
__global__ __launch_bounds__(1024)
void fft64_col_b4(const float* __restrict__ wsf, float* __restrict__ out) {
    __shared__ float2 xch[8192];            // pane_h = h*4096, 64 KB
    const int c  = threadIdx.x & 63;
    const int v  = (threadIdx.x >> 6) & 7;  // 0..7
    const int h  = threadIdx.x >> 9;        // 0,1
    const int qa = blockIdx.x;              // 0..31
    const int T  = blockIdx.y;              // 0..31
    const int q  = (h == 0) ? qa : ((qa == 0) ? 32 : 64 - qa);
    const bool self0 = (qa == 0);
    const int pane = h * 4096;
    const int ppane = (self0 ? h : 1 - h) * 4096;

    const float2* wsc = reinterpret_cast<const float2*>(wsf);
    const size_t cbase = (size_t)T * 64 + c;

    // load own half's H: g_u = H[q][8u+v][T*64+c]
#define LDH(u) float2 g##u = wsc[(size_t)q * 131072 + (size_t)(8*u+v) * 2048 + cbase];
    FOR8(LDH)
#undef LDH

    float2 wv; __sincosf((float)v * -0.09817477042468103f, &wv.y, &wv.x);

    FFT8N(g)                                // over u
#define W1(k) xch[pane + v * 512 + k * 64 + c] = g##k;
    FOR8(W1)
#undef W1
    __syncthreads();                        // bar1
#define R1b(vv) g##vv = xch[pane + vv * 512 + v * 64 + c];
    FOR8(R1b)
#undef R1b
    __syncthreads();                        // bar2 (WAR: pane reused for G)
    TWCHAIN(g, wv)
    FFT8N(g)                                // -> G_h[8a+v] in g_a

#define WG(a) xch[pane + (8*a + v) * 64 + c] = g##a;
    FOR8(WG)
#undef WG
    __syncthreads();                        // bar3

    // combine + expk + store for rows q (this half)
    const float2 STEP = make_float2(0.98078528040323045f, 0.19509032201612827f); // e^{+i pi/16}
    float2 e; __sincosf((float)(64 * v + q) * 3.8349519697141029e-4f, &e.y, &e.x);
    const int colA = T * 128 + c;

#define CMB(a) { \
    const int p_ = 8 * a + v; \
    const int pi_ = (q == 0) ? ((64 - p_) & 63) : (63 - p_); \
    float2 rq = xch[ppane + pi_ * 64 + c]; \
    float FAx = 0.5f * (g##a.x + rq.x), FAy = 0.5f * (g##a.y - rq.y); \
    float FBx = 0.5f * (g##a.y + rq.y), FBy = 0.5f * (rq.x - g##a.x); \
    size_t rowq = (size_t)(512 * a + 64 * v + q) * L; \
    out[rowq + colA]      = FAx * e.x + FAy * e.y; \
    out[rowq + colA + 64] = FBx * e.x + FBy * e.y; \
    e = cmul(e, STEP); }
    FOR8(CMB)
#undef CMB
}

extern "C" void kernel_launch(void* const* d_in, const int* in_sizes, int n_in,
                              void* d_out, int out_size, void* d_ws, size_t ws_size,
                              hipStream_t stream) {
    const float* x = (const float*)d_in[0];
    float* out = (float*)d_out;
    float* ws  = (float*)d_ws;   // needs 64 MB

    dct_rows4_kernel<<<L / 2, 512, 0, stream>>>(x, out);        // rows: x -> Y(out)
    fft64_col_a2<<<dim3(64, 32), 512, 0, stream>>>(out, ws);    // Y -> H(ws)
    fft64_col_b4<<<dim3(32, 32), 1024, 0, stream>>>(ws, out);   // H -> final(out)
}

// Round 20
// 72.612 us; speedup vs baseline: 1.0152x; 1.0152x over previous
//
#include <hip/hip_runtime.h>
#include <hip/hip_bf16.h>

// 2D DCT-II (4096x4096 fp32).  Round 20:
//   K1  = dct_rows4 v4: coalesced float2 Makhoul loads (8 loads/thread,
//         512B/wave) + minimal 4-float2 LDS exchange for the reflected
//         halves (slots [2047-n], stride-1 both sides), replacing R18's
//         16 stride-2 scalar loads / R16's full 16-op LDS distribute.
//         9 barriers, 33KB pane, 4 blocks/CU.
//   K2a = cooperative column step 1 (unchanged)
//   K2b = v4 parallel-halves column step 2 (unchanged)
// Plan: K1(x->out) ; K2a(out->ws) ; K2b(ws->out).  d_ws needs 64 MB.

#define L 4096

__device__ __forceinline__ float2 cmul(float2 a, float2 b) {
    return make_float2(a.x * b.x - a.y * b.y, a.x * b.y + a.y * b.x);
}

__device__ __forceinline__ void bfly4(float2& x0, float2& x1, float2& x2, float2& x3) {
    float t0x = x0.x + x2.x, t0y = x0.y + x2.y;
    float t1x = x0.x - x2.x, t1y = x0.y - x2.y;
    float t2x = x1.x + x3.x, t2y = x1.y + x3.y;
    float t3x = x1.x - x3.x, t3y = x1.y - x3.y;
    x0 = make_float2(t0x + t2x, t0y + t2y);
    x1 = make_float2(t1x + t3y, t1y - t3x);   // t1 + (-i)*t3
    x2 = make_float2(t0x - t2x, t0y - t2y);
    x3 = make_float2(t1x - t3y, t1y + t3x);   // t1 + (+i)*t3
}

#define FOR4(X) X(0) X(1) X(2) X(3)
#define FOR8(X) X(0) X(1) X(2) X(3) X(4) X(5) X(6) X(7)

// 8-point DFT on named regs P0..P7, natural in -> natural out (DIT):
#define FFT8N(P) \
  bfly4(P##0, P##2, P##4, P##6); \
  bfly4(P##1, P##3, P##5, P##7); \
  { float2 e1_=P##2, e2_=P##4, e3_=P##6, o0_=P##1, o1_=P##3, o2_=P##5, o3_=P##7; \
    o1_ = cmul(o1_, make_float2(0.70710678118654752f, -0.70710678118654752f)); \
    o2_ = make_float2(o2_.y, -o2_.x); \
    o3_ = cmul(o3_, make_float2(-0.70710678118654752f, -0.70710678118654752f)); \
    float2 e0_=P##0; \
    P##0 = make_float2(e0_.x+o0_.x, e0_.y+o0_.y); \
    P##4 = make_float2(e0_.x-o0_.x, e0_.y-o0_.y); \
    P##1 = make_float2(e1_.x+o1_.x, e1_.y+o1_.y); \
    P##5 = make_float2(e1_.x-o1_.x, e1_.y-o1_.y); \
    P##2 = make_float2(e2_.x+o2_.x, e2_.y+o2_.y); \
    P##6 = make_float2(e2_.x-o2_.x, e2_.y-o2_.y); \
    P##3 = make_float2(e3_.x+o3_.x, e3_.y+o3_.y); \
    P##7 = make_float2(e3_.x-o3_.x, e3_.y-o3_.y); }

#define TWCHAIN(P, W) { float2 f_ = W; \
    P##1 = cmul(P##1, f_); f_ = cmul(f_, W); \
    P##2 = cmul(P##2, f_); f_ = cmul(f_, W); \
    P##3 = cmul(P##3, f_); f_ = cmul(f_, W); \
    P##4 = cmul(P##4, f_); f_ = cmul(f_, W); \
    P##5 = cmul(P##5, f_); f_ = cmul(f_, W); \
    P##6 = cmul(P##6, f_); f_ = cmul(f_, W); \
    P##7 = cmul(P##7, f_); }

// ---------------- K1: cooperative row DCT, v4 ----------------
// Thread (l = lane 0..63, v = wave 0..7).  n = 64a + b, a = 8u+v, b = l.
// float2 at x[2n] (n<2048) = (v[n], v[4095-n]); the .y half is exchanged
// through pane slots [2047-n] to its owner (63-l, 7-v) as g_{7-u}.
__global__ __launch_bounds__(512)
void dct_rows4_kernel(const float* __restrict__ in, float* __restrict__ out) {
    __shared__ float2 xch[4160];            // 33,280 B -> 4 blocks/CU
    const int l = threadIdx.x & 63;
    const int v = threadIdx.x >> 6;
    const int r0 = blockIdx.x * 2;
    const float* rowA = in + (size_t)r0 * L;
    const float* rowB = rowA + L;

    // coalesced Makhoul load: u<4 direct, .y halves exchanged via LDS
#define DECLG(u) float2 g##u;
    FOR8(DECLG)
#undef DECLG
#define LDX(u) { \
        const int n = 512*u + 64*v + l; \
        float2 fa = *reinterpret_cast<const float2*>(&rowA[2*n]); \
        float2 fb = *reinterpret_cast<const float2*>(&rowB[2*n]); \
        g##u = make_float2(fa.x, fb.x); \
        xch[2047 - n] = make_float2(fa.y, fb.y); }
    FOR4(LDX)
#undef LDX
    __syncthreads();                        // B0a: exchange visible
    {
        const int base = 64*v + l - 2048;
        g4 = xch[512*4 + base];
        g5 = xch[512*5 + base];
        g6 = xch[512*6 + base];
        g7 = xch[512*7 + base];
    }
    __syncthreads();                        // B0b (WAR: pane reused below)

    // ---- FFT64 over a (a = 8u+v), fixed b = l ----
    FFT8N(g)
#define W2(t) xch[512*v + 64*t + l] = g##t;
    FOR8(W2)
#undef W2
    __syncthreads();                        // B1
#define R2(vv) g##vv = xch[512*vv + 64*v + l];
    FOR8(R2)
#undef R2
    __syncthreads();                        // B2 (WAR)

    float2 wv; __sincosf((float)v * -0.09817477042468103f, &wv.y, &wv.x); // -2pi v/64
    TWCHAIN(g, wv)
    FFT8N(g)                                // -> H[q = 8s+v][b = l] in g_s

    // mid twiddle W4096^{l*q}: anchor e^{-2pi l v/4096}, step e^{-pi l/256}
    float2 mw, ms;
    __sincosf((float)(l * v) * -1.5339807878856412e-3f, &mw.y, &mw.x);
    __sincosf((float)l * -1.2271846303085130e-2f, &ms.y, &ms.x);
#define W3(s) { g##s = cmul(g##s, mw); xch[520*s + 65*v + l] = g##s; mw = cmul(mw, ms); }
    FOR8(W3)
#undef W3
    __syncthreads();                        // B3
#define R3(u) g##u = xch[65*l + 8*u + v];
    FOR8(R3)
#undef R3
    __syncthreads();                        // B4 (WAR)

    // ---- FFT64 over b (b = 8u+v), fixed q = l ----
    FFT8N(g)
#define W4(t) xch[512*v + 64*t + l] = g##t;
    FOR8(W4)
#undef W4
    __syncthreads();                        // B5
#define R4(vv) g##vv = xch[512*vv + 64*v + l];
    FOR8(R4)
#undef R4
    __syncthreads();                        // B6 (WAR)

    TWCHAIN(g, wv)
    FFT8N(g)                                // -> X[512s + 64v + l] in g_s

    // pane [p][q] (pad 65), p = 8s+v, q = l
#define W5(s) xch[520*s + 65*v + l] = g##s;
    FOR8(W5)
#undef W5
    __syncthreads();                        // B7

    // epilogue: conj-split + expk.  k = 512s + 64v + l, partner m = (4096-k)&4095
    float* outA = out + (size_t)r0 * L;
    float* outB = outA + L;
    float2 e; __sincosf((float)(64*v + l) * 3.8349519697141029e-4f, &e.y, &e.x); // pi k0/8192
    const float2 ST = make_float2(0.98078528040323045f, 0.19509032201612827f);   // e^{i pi/16}
#define EP5(s) { \
        const int k = 512*s + 64*v + l; \
        const int m = (4096 - k) & 4095; \
        float2 Zk = g##s; \
        float2 Zm = xch[(m >> 6) * 65 + (m & 63)]; \
        float vax = 0.5f*(Zk.x + Zm.x), vay = 0.5f*(Zk.y - Zm.y); \
        float vbx = 0.5f*(Zk.y + Zm.y), vby = 0.5f*(Zm.x - Zk.x); \
        outA[k] = vax*e.x + vay*e.y; \
        outB[k] = vbx*e.x + vby*e.y; \
        e = cmul(e, ST); }
    FOR8(EP5)
#undef EP5
}

// ---------------- K2a: cooperative column pass, step 1 (unchanged) ----------------
__global__ __launch_bounds__(512)
void fft64_col_a2(const float* __restrict__ Y, float* __restrict__ ws) {
    __shared__ float2 xch[4096];            // [v][t][c], 32 KB
    const int c = threadIdx.x & 63;
    const int v = threadIdx.x >> 6;         // 0..7
    const int b = blockIdx.x;               // 0..63
    const int T = blockIdx.y;               // 0..31
    const int ca = T * 128 + c;
    const int cb = ca + 64;

#define LDA(u) float2 g##u; { \
        const int aa = 8 * u + v; \
        const int row = (u < 4) ? (128 * aa + 2 * b) : (8191 - 128 * aa - 2 * b); \
        const float* rp = Y + (size_t)row * L; \
        g##u = make_float2(rp[ca], rp[cb]); }
    FOR8(LDA)
#undef LDA

    FFT8N(g)                                // over u -> G[t][v] in g_t

#define WRA(t) xch[v * 512 + t * 64 + c] = g##t;
    FOR8(WRA)
#undef WRA
    __syncthreads();
#define RDA(vv) g##vv = xch[vv * 512 + v * 64 + c];
    FOR8(RDA)
#undef RDA

    float2 wv; __sincosf((float)v * -0.09817477042468103f, &wv.y, &wv.x); // -2pi v/64
    TWCHAIN(g, wv)

    FFT8N(g)                                // -> Z[q], q = 8s+v, in g_s

    float2 mw, ms;
    __sincosf((float)(b * v) * -1.5339807878856412e-3f, &mw.y, &mw.x);
    __sincosf((float)b * -1.2271846303085130e-2f, &ms.y, &ms.x);   // -pi b/256
    float2* wp = reinterpret_cast<float2*>(ws) + (size_t)b * 2048 + (size_t)T * 64 + c;
#define STA(s) { \
        g##s = cmul(g##s, mw); \
        wp[(size_t)(8 * s + v) * 131072] = g##s; \
        mw = cmul(mw, ms); }
    FOR8(STA)
#undef STA
}

// ---------------- K2b v4: parallel-halves column pass, step 2 (unchanged) ----------------
__global__ __launch_bounds__(1024)
void fft64_col_b4(const float* __restrict__ wsf, float* __restrict__ out) {
    __shared__ float2 xch[8192];            // pane_h = h*4096, 64 KB
    const int c  = threadIdx.x & 63;
    const int v  = (threadIdx.x >> 6) & 7;  // 0..7
    const int h  = threadIdx.x >> 9;        // 0,1
    const int qa = blockIdx.x;              // 0..31
    const int T  = blockIdx.y;              // 0..31
    const int q  = (h == 0) ? qa : ((qa == 0) ? 32 : 64 - qa);
    const bool self0 = (qa == 0);
    const int pane = h * 4096;
    const int ppane = (self0 ? h : 1 - h) * 4096;

    const float2* wsc = reinterpret_cast<const float2*>(wsf);
    const size_t cbase = (size_t)T * 64 + c;

#define LDH(u) float2 g##u = wsc[(size_t)q * 131072 + (size_t)(8*u+v) * 2048 + cbase];
    FOR8(LDH)
#undef LDH

    float2 wv; __sincosf((float)v * -0.09817477042468103f, &wv.y, &wv.x);

    FFT8N(g)                                // over u
#define W1(k) xch[pane + v * 512 + k * 64 + c] = g##k;
    FOR8(W1)
#undef W1
    __syncthreads();                        // bar1
#define R1b(vv) g##vv = xch[pane + vv * 512 + v * 64 + c];
    FOR8(R1b)
#undef R1b
    __syncthreads();                        // bar2 (WAR)
    TWCHAIN(g, wv)
    FFT8N(g)                                // -> G_h[8a+v] in g_a

#define WG(a) xch[pane + (8*a + v) * 64 + c] = g##a;
    FOR8(WG)
#undef WG
    __syncthreads();                        // bar3

    const float2 STEP = make_float2(0.98078528040323045f, 0.19509032201612827f); // e^{+i pi/16}
    float2 e; __sincosf((float)(64 * v + q) * 3.8349519697141029e-4f, &e.y, &e.x);
    const int colA = T * 128 + c;

#define CMB(a) { \
    const int p_ = 8 * a + v; \
    const int pi_ = (q == 0) ? ((64 - p_) & 63) : (63 - p_); \
    float2 rq = xch[ppane + pi_ * 64 + c]; \
    float FAx = 0.5f * (g##a.x + rq.x), FAy = 0.5f * (g##a.y - rq.y); \
    float FBx = 0.5f * (g##a.y + rq.y), FBy = 0.5f * (rq.x - g##a.x); \
    size_t rowq = (size_t)(512 * a + 64 * v + q) * L; \
    out[rowq + colA]      = FAx * e.x + FAy * e.y; \
    out[rowq + colA + 64] = FBx * e.x + FBy * e.y; \
    e = cmul(e, STEP); }
    FOR8(CMB)
#undef CMB
}

extern "C" void kernel_launch(void* const* d_in, const int* in_sizes, int n_in,
                              void* d_out, int out_size, void* d_ws, size_t ws_size,
                              hipStream_t stream) {
    const float* x = (const float*)d_in[0];
    float* out = (float*)d_out;
    float* ws  = (float*)d_ws;   // needs 64 MB

    dct_rows4_kernel<<<L / 2, 512, 0, stream>>>(x, out);        // rows: x -> Y(out)
    fft64_col_a2<<<dim3(64, 32), 512, 0, stream>>>(out, ws);    // Y -> H(ws)
    fft64_col_b4<<<dim3(32, 32), 1024, 0, stream>>>(ws, out);   // H -> final(out)
}